// Round 14
// baseline (300.501 us; speedup 1.0000x reference)
//
#include <hip/hip_runtime.h>
#include <hip/hip_fp16.h>

// RoIAlign3D: features (B=2, C=256, 64,64,64) f32, proposals (B=2, N=512, 6) f32
// out: (B*N, C, 7, 7, 7) f32
//
// kernel1: bucket 3584 (roi,iz) entries per batch by z0=floor(gz) into CSR +
//   32 B record {x1p,sx,y1p,sy, wz,out_off,-,-}.
// kernel2 (R12 base + unroll-2): block = (z0, slice), 512 thr, 33.8 KB LDS
//   -> 4 blocks/CU. Stage planes z0,z0+1 as z-pair f16 slots:
//   slot64(y,x) = {pk(h[x],h[x+1])@z0, pk(...)@z0+1}; ONE ds_read2_b64 ->
//   all 8 corners. Dense lane map (g=tid/49, p=tid%49): stores are 49-float
//   contiguous segments (best store-TA shape measured, R12 vs R13).
//   ENTRY LOOP UNROLLED 2x with independent register sets: store-data regs
//   rotate 2-deep (no per-iteration vmcnt store-ack drain) and two
//   independent LDS->lerp chains per wave (cross-pipe overlap). The
//   sum-of-pipes model (VALU~114us + LDS~125us + storeTA~25us ~= 290us
//   observed) says overlap, not issue count, is the remaining lever.
// Coords in [0,63): floor<=62, +1<=63 -> no clamping; slot x=63's upper
//   half is garbage but never read (x0<=62).

#define B_      2
#define C_      256
#define N_      512
#define NENT    (N_ * 7)
#define SP      66                  // slots per row (64 used + 2 pad)
#define THREADS 512
#define GROUPS  10                  // 10*49 = 490 active lanes
#define REC_F_BASE 128
#define WS_NEEDED ((size_t)REC_F_BASE * 4 + (size_t)B_ * NENT * 8 * 4)

typedef _Float16 h2v __attribute__((ext_vector_type(2)));

__device__ __forceinline__ float gcoord(float lo, float hi, int i) {
    return lo + (hi - lo) * (1.0f / 6.0f) * (float)i;
}

__device__ __forceinline__ uint32_t pkrtz(float a, float b) {
    auto h = __builtin_amdgcn_cvt_pkrtz(a, b);
    return __builtin_bit_cast(uint32_t, h);
}

// (1-wx)*v.lo + wx*v.hi with f32 accumulation
__device__ __forceinline__ float xlerp(uint32_t pkv, uint32_t pkw) {
#if __has_builtin(__builtin_amdgcn_fdot2)
    return __builtin_amdgcn_fdot2(__builtin_bit_cast(h2v, pkv),
                                  __builtin_bit_cast(h2v, pkw), 0.0f, false);
#else
    h2v v = __builtin_bit_cast(h2v, pkv);
    h2v w = __builtin_bit_cast(h2v, pkw);
    return (float)v[0] * (float)w[0] + (float)v[1] * (float)w[1];
#endif
}

// ---- kernel 1: bucket + per-entry record ----
__global__ __launch_bounds__(256) void bucket_kernel(
    const float* __restrict__ props, int* __restrict__ wsi, float* __restrict__ wsf)
{
    int b = blockIdx.x;
    __shared__ int counts[63];
    __shared__ int starts[64];
    __shared__ int cursors[63];
    int tid = threadIdx.x;
    if (tid < 63) counts[tid] = 0;
    __syncthreads();
    for (int e = tid; e < NENT; e += 256) {
        int n = e / 7, iz = e - n * 7;
        const float* pr = props + (size_t)(b * N_ + n) * 6;
        float gz = gcoord(pr[2], pr[5], iz);
        int z0 = min(max((int)gz, 0), 62);
        atomicAdd(&counts[z0], 1);
    }
    __syncthreads();
    if (tid == 0) {
        int s = 0;
        for (int k = 0; k < 63; ++k) { starts[k] = s; s += counts[k]; }
        starts[63] = s;
    }
    __syncthreads();
    if (tid < 63) cursors[tid] = starts[tid];
    __syncthreads();
    for (int e = tid; e < NENT; e += 256) {
        int n = e / 7, iz = e - n * 7;
        const float* pr = props + (size_t)(b * N_ + n) * 6;
        float x1p = pr[0], y1p = pr[1], z1p = pr[2];
        float x2p = pr[3], y2p = pr[4], z2p = pr[5];
        float gz = gcoord(z1p, z2p, iz);
        int z0 = min(max((int)gz, 0), 62);
        float wz = gz - (float)z0;
        int pos = atomicAdd(&cursors[z0], 1);
        int off = (b * N_ + n) * (C_ * 343) + iz * 49;
        float* r = wsf + REC_F_BASE + (size_t)(b * NENT + pos) * 8;
        r[0] = x1p; r[1] = (x2p - x1p) * (1.0f / 6.0f);
        r[2] = y1p; r[3] = (y2p - y1p) * (1.0f / 6.0f);
        r[4] = wz;  r[5] = __int_as_float(off);
        r[6] = 0.0f; r[7] = 0.0f;
    }
    if (tid < 64) wsi[b * 64 + tid] = starts[tid];
}

// ---- kernel 2: block = (z0, slice); dense-p; unroll-2 entry loop ----
__global__ __launch_bounds__(THREADS, 8) void roialign3d_u2_kernel(
    const float* __restrict__ feat,
    const int* __restrict__ wsi,
    const float* __restrict__ wsf,
    float* __restrict__ out)
{
    __shared__ __align__(16) uint2 pk2[64 * SP];   // 33792 B -> 4 blocks/CU

    int bid = blockIdx.x;
    int s   = bid & 511;           // slice fastest -> slice s on XCD s%8 always
    int z0  = bid >> 9;            // 0..62
    int b   = s >> 8;
    int c   = s & 255;
    int tid = threadIdx.x;

    int base = wsi[b * 64 + z0];
    int end  = wsi[b * 64 + z0 + 1];
    if (base == end) return;       // empty bucket: skip staging entirely

    const float* vol = feat + ((size_t)s << 18) + ((size_t)z0 << 12);

    // ---- stage: 2 planes (32 KB) of one slice; 4 float4 loads/thread ----
    int y  = tid >> 3;
    int x8 = (tid & 7) << 3;
    const float* src = vol + y * 64 + x8;
    float4 p0a = *(const float4*)(src);
    float4 p0b = *(const float4*)(src + 4);
    float4 p1a = *(const float4*)(src + 4096);
    float4 p1b = *(const float4*)(src + 4100);

    // dense lane map + record prefetch (behind plane loads)
    int g = tid / 49;
    int p = tid - g * 49;
    int iy = p / 7;
    float fx = (float)(p - iy * 7);
    float fy = (float)iy;
    const float4* recs2 = (const float4*)(wsf + REC_F_BASE) + (size_t)(b * NENT) * 2;
    int myEnd = (g < GROUPS) ? end : base;
    int e = base + g;
    float4 r0A, r0B, r1A, r1B;
    if (e < myEnd) {
        r0A = recs2[(size_t)e * 2];
        r0B = recs2[(size_t)e * 2 + 1];
        if (e + GROUPS < myEnd) {
            r1A = recs2[(size_t)(e + GROUPS) * 2];
            r1B = recs2[(size_t)(e + GROUPS) * 2 + 1];
        }
    }

    // ---- convert + write: slot64(y,x) = {xpair@z0, xpair@z0+1} ----
    {
        float n0 = __shfl_down(p0a.x, 1);   // next thread's first f32, plane z0
        float n1 = __shfl_down(p1a.x, 1);   // (garbage at row edge: slot x=63
                                            //  upper half, never read)
        uint4* d = (uint4*)&pk2[y * SP + x8];
        uint4 w0, w1, w2, w3;
        w0.x = pkrtz(p0a.x, p0a.y); w0.y = pkrtz(p1a.x, p1a.y);
        w0.z = pkrtz(p0a.y, p0a.z); w0.w = pkrtz(p1a.y, p1a.z);
        w1.x = pkrtz(p0a.z, p0a.w); w1.y = pkrtz(p1a.z, p1a.w);
        w1.z = pkrtz(p0a.w, p0b.x); w1.w = pkrtz(p1a.w, p1b.x);
        w2.x = pkrtz(p0b.x, p0b.y); w2.y = pkrtz(p1b.x, p1b.y);
        w2.z = pkrtz(p0b.y, p0b.z); w2.w = pkrtz(p1b.y, p1b.z);
        w3.x = pkrtz(p0b.z, p0b.w); w3.y = pkrtz(p1b.z, p1b.w);
        w3.z = pkrtz(p0b.w, n0);    w3.w = pkrtz(p1b.w, n1);
        d[0] = w0; d[1] = w1; d[2] = w2; d[3] = w3;
    }
    __syncthreads();

    // ---- entry loop, unroll 2: independent chains, 2-deep store rotation ----
    float* outc = out + (size_t)c * 343;
    while (e + GROUPS < myEnd) {
        int eN = e + 2 * GROUPS;
        float4 n0A, n0B, n1A, n1B;
        if (eN < myEnd) {
            n0A = recs2[(size_t)eN * 2];
            n0B = recs2[(size_t)eN * 2 + 1];
            if (eN + GROUPS < myEnd) {
                n1A = recs2[(size_t)(eN + GROUPS) * 2];
                n1B = recs2[(size_t)(eN + GROUPS) * 2 + 1];
            }
        }
        // entry 0 address+weights
        float gx0 = fmaf(r0A.y, fx, r0A.x);
        float gy0 = fmaf(r0A.w, fy, r0A.z);
        int x00 = (int)gx0, y00 = (int)gy0;
        float wx0 = __builtin_amdgcn_fractf(gx0);
        float wy0 = __builtin_amdgcn_fractf(gy0);
        uint32_t pw0 = pkrtz(1.0f - wx0, wx0);
        int sl0 = y00 * SP + x00;
        uint2 qa0 = pk2[sl0], qa1 = pk2[sl0 + SP];
        // entry 1 address+weights (independent chain)
        float gx1 = fmaf(r1A.y, fx, r1A.x);
        float gy1 = fmaf(r1A.w, fy, r1A.z);
        int x10 = (int)gx1, y10 = (int)gy1;
        float wx1 = __builtin_amdgcn_fractf(gx1);
        float wy1 = __builtin_amdgcn_fractf(gy1);
        uint32_t pw1 = pkrtz(1.0f - wx1, wx1);
        int sl1 = y10 * SP + x10;
        uint2 qb0 = pk2[sl1], qb1 = pk2[sl1 + SP];
        // entry 0 lerps + store
        {
            float c00 = xlerp(qa0.x, pw0);
            float c10 = xlerp(qa0.y, pw0);
            float c01 = xlerp(qa1.x, pw0);
            float c11 = xlerp(qa1.y, pw0);
            float d0 = fmaf(c01 - c00, wy0, c00);
            float d1 = fmaf(c11 - c10, wy0, c10);
            outc[__float_as_int(r0B.y) + p] = fmaf(d1 - d0, r0B.x, d0);
        }
        // entry 1 lerps + store
        {
            float c00 = xlerp(qb0.x, pw1);
            float c10 = xlerp(qb0.y, pw1);
            float c01 = xlerp(qb1.x, pw1);
            float c11 = xlerp(qb1.y, pw1);
            float d0 = fmaf(c01 - c00, wy1, c00);
            float d1 = fmaf(c11 - c10, wy1, c10);
            outc[__float_as_int(r1B.y) + p] = fmaf(d1 - d0, r1B.x, d0);
        }
        e = eN; r0A = n0A; r0B = n0B; r1A = n1A; r1B = n1B;
    }
    // tail: at most one entry left for this group
    if (e < myEnd) {
        float gx = fmaf(r0A.y, fx, r0A.x);
        float gy = fmaf(r0A.w, fy, r0A.z);
        int x0 = (int)gx, y0 = (int)gy;
        float wx = __builtin_amdgcn_fractf(gx);
        float wy = __builtin_amdgcn_fractf(gy);
        uint32_t pw = pkrtz(1.0f - wx, wx);
        int sl = y0 * SP + x0;
        uint2 q0 = pk2[sl], q1 = pk2[sl + SP];
        float c00 = xlerp(q0.x, pw);
        float c10 = xlerp(q0.y, pw);
        float c01 = xlerp(q1.x, pw);
        float c11 = xlerp(q1.y, pw);
        float d0 = fmaf(c01 - c00, wy, c00);
        float d1 = fmaf(c11 - c10, wy, c10);
        outc[__float_as_int(r0B.y) + p] = fmaf(d1 - d0, r0B.x, d0);
    }
}

// ---- fallback (ws too small): round-1 kernel, known correct ----
__global__ __launch_bounds__(128) void roialign3d_fallback(
    const float* __restrict__ feat, const float* __restrict__ props,
    float* __restrict__ out)
{
    int bid = blockIdx.x;
    int xcd = bid & 7;
    int j   = bid >> 3;
    int s   = xcd + ((j >> 9) << 3);
    int n   = j & 511;
    int b   = s >> 8;
    int c   = s & 255;
    const float* prop = props + ((size_t)(b * N_ + n)) * 6;
    float x1p = prop[0], y1p = prop[1], z1p = prop[2];
    float x2p = prop[3], y2p = prop[4], z2p = prop[5];
    float sx = (x2p - x1p) * (1.0f / 6.0f);
    float sy = (y2p - y1p) * (1.0f / 6.0f);
    float sz = (z2p - z1p) * (1.0f / 6.0f);
    const float* vol = feat + (size_t)s * (64 * 64 * 64);
    float* o = out + ((size_t)(b * N_ + n) * C_ + c) * 343;
    for (int p = threadIdx.x; p < 343; p += 128) {
        int iz = p / 49, r = p - iz * 49, iy = r / 7, ix = r - iy * 7;
        float gx = x1p + sx * ix, gy = y1p + sy * iy, gz = z1p + sz * iz;
        int x0 = (int)gx, y0 = (int)gy, z0 = (int)gz;
        float wx = gx - x0, wy = gy - y0, wz = gz - z0;
        int x1 = min(x0 + 1, 63), y1 = min(y0 + 1, 63), z1 = min(z0 + 1, 63);
        const float* p00 = vol + ((z0 * 64 + y0) << 6);
        const float* p01 = vol + ((z0 * 64 + y1) << 6);
        const float* p10 = vol + ((z1 * 64 + y0) << 6);
        const float* p11 = vol + ((z1 * 64 + y1) << 6);
        float c00 = p00[x0] + (p00[x1] - p00[x0]) * wx;
        float c01 = p01[x0] + (p01[x1] - p01[x0]) * wx;
        float c10 = p10[x0] + (p10[x1] - p10[x0]) * wx;
        float c11 = p11[x0] + (p11[x1] - p11[x0]) * wx;
        float d0 = c00 + (c01 - c00) * wy;
        float d1 = c10 + (c11 - c10) * wy;
        o[p] = d0 + (d1 - d0) * wz;
    }
}

extern "C" void kernel_launch(void* const* d_in, const int* in_sizes, int n_in,
                              void* d_out, int out_size, void* d_ws, size_t ws_size,
                              hipStream_t stream) {
    const float* feat  = (const float*)d_in[0];
    const float* props = (const float*)d_in[1];
    float* out = (float*)d_out;

    if (ws_size < WS_NEEDED) {
        roialign3d_fallback<<<B_ * C_ * N_, 128, 0, stream>>>(feat, props, out);
        return;
    }
    int*   wsi = (int*)d_ws;
    float* wsf = (float*)d_ws;
    bucket_kernel<<<B_, 256, 0, stream>>>(props, wsi, wsf);
    roialign3d_u2_kernel<<<63 * 512, THREADS, 0, stream>>>(feat, wsi, wsf, out);
}